// Round 15
// baseline (146.028 us; speedup 1.0000x reference)
//
#include <hip/hip_runtime.h>
#include <hip/hip_bf16.h>

// PointInstanceNorm: per-(segment, channel) normalization over [1, N, C] fp32,
// S contiguous equal segments. Best 137.0 us (R12). Ledger:
//   K1 ~77us (268MB cold-HBM read @ 3.5 TB/s), K2+ovh ~5us, K3 ~55us.
// Read-cap evidence: 3.5 TB/s invariant across chunked single/dual/quad-stream
// and sliding-window (R9/R12/R13/R14). Last untested lever: OCCUPANCY.
// This round, ONE variable vs R12: K1 16 -> 32 waves/CU
//   (ppb 1024 -> 512: grid 2048 = 8 blocks/CU; __launch_bounds__(256,8)
//    caps VGPR <= 64 so full residency is achievable).
// R11's apparent evidence against more blocks was confounded by the then-
// serial K2 (512 dependent fold iters); K2 has been parallel since R12.
//   K2: parallel fold (4 threads/channel + LDS tree) [R12].
//   K3: y = x*scale + shift, ascending; PLAIN x loads (L3-served), NT stores
//       (write stream must not evict x). FROZEN since R7.

#define EPS 1e-5f

typedef float f32x4 __attribute__((ext_vector_type(4)));  // nt builtins reject HIP_vector_type

// ---------------------------------------------------------------- kernel 1
// 256 threads (4 waves), PPB=512 contiguous points per chunk. Lane l reads
// the float4 of channels 4*(l&15)..+3 of point base+(l>>4): a wave covers
// 1KB contiguous per load. Fast path walks TWO streams (it, it+half ->
// 64KB apart), separate accumulators (R12: 2 streams beat 1 and 4).
// Chunk index reversed (descending sweep keeps x head most-recent in L3).
__global__ __launch_bounds__(256, 8) void pin_stats(
    const float4* __restrict__ x4, float* __restrict__ partials,
    int ppb, long N) {
    const int tid   = threadIdx.x;
    const int lane  = tid & 63;
    const int wave  = tid >> 6;
    const int cgrp  = lane & 15;
    const int quart = lane >> 4;
    const long bchunk = (long)gridDim.x - 1 - blockIdx.x;   // descending sweep
    const long block_start = bchunk * ppb;

    float4 s = make_float4(0.f, 0.f, 0.f, 0.f);
    float4 q = make_float4(0.f, 0.f, 0.f, 0.f);

    const int iters = ppb >> 4;
    const long lane_base = (block_start + wave * 4 + quart) * 16 + cgrp;

    if (block_start + ppb <= N && (iters & 1) == 0) {
        const int half = iters >> 1;                  // 16 at ppb=512
        float4 s1 = make_float4(0.f, 0.f, 0.f, 0.f);
        float4 q1 = make_float4(0.f, 0.f, 0.f, 0.f);
        #pragma unroll 4
        for (int it = 0; it < half; ++it) {
            float4 a = x4[lane_base + (long)it * 256];
            float4 b = x4[lane_base + (long)(it + half) * 256];
            s.x  += a.x; s.y  += a.y; s.z  += a.z; s.w  += a.w;
            q.x  += a.x * a.x; q.y  += a.y * a.y; q.z  += a.z * a.z; q.w  += a.w * a.w;
            s1.x += b.x; s1.y += b.y; s1.z += b.z; s1.w += b.w;
            q1.x += b.x * b.x; q1.y += b.y * b.y; q1.z += b.z * b.z; q1.w += b.w * b.w;
        }
        s.x += s1.x; s.y += s1.y; s.z += s1.z; s.w += s1.w;
        q.x += q1.x; q.y += q1.y; q.z += q1.z; q.w += q1.w;
    } else {
        for (int it = 0; it < iters; ++it) {
            long p = block_start + (long)it * 16 + wave * 4 + quart;
            if (p < N) {
                float4 v = x4[p * 16 + cgrp];
                s.x += v.x; s.y += v.y; s.z += v.z; s.w += v.w;
                q.x += v.x * v.x; q.y += v.y * v.y; q.z += v.z * v.z; q.w += v.w * v.w;
            }
        }
    }

    #pragma unroll
    for (int off = 16; off <= 32; off <<= 1) {
        s.x += __shfl_xor(s.x, off); s.y += __shfl_xor(s.y, off);
        s.z += __shfl_xor(s.z, off); s.w += __shfl_xor(s.w, off);
        q.x += __shfl_xor(q.x, off); q.y += __shfl_xor(q.y, off);
        q.z += __shfl_xor(q.z, off); q.w += __shfl_xor(q.w, off);
    }

    __shared__ float lds[4][16][8];
    if (lane < 16) {
        lds[wave][lane][0] = s.x; lds[wave][lane][1] = s.y;
        lds[wave][lane][2] = s.z; lds[wave][lane][3] = s.w;
        lds[wave][lane][4] = q.x; lds[wave][lane][5] = q.y;
        lds[wave][lane][6] = q.z; lds[wave][lane][7] = q.w;
    }
    __syncthreads();

    if (tid < 128) {
        int stat = tid >> 6;
        int ch   = tid & 63;
        int cg   = ch >> 2;
        int j    = ch & 3;
        float v = lds[0][cg][stat * 4 + j] + lds[1][cg][stat * 4 + j]
                + lds[2][cg][stat * 4 + j] + lds[3][cg][stat * 4 + j];
        partials[bchunk * 128 + tid] = v;
    }
}

// ---------------------------------------------------------------- kernel 2
// One block per segment, 256 threads: 4 threads per channel fold interleaved
// chunk subsets, then a fixed-order LDS tree combines the 4 sub-partials.
__global__ __launch_bounds__(256) void pin_scale(
    const float* __restrict__ partials,
    const float* __restrict__ weight, const float* __restrict__ bias,
    const int* __restrict__ offs,
    float* __restrict__ scale, float* __restrict__ shift, int ppb) {
    const int s = blockIdx.x;
    const int c = threadIdx.x & 63;
    const int r = threadIdx.x >> 6;          // 0..3
    const int b0 = offs[s] / ppb;
    const int b1 = offs[s + 1] / ppb;

    float sum = 0.f, sq = 0.f;
    for (int blk = b0 + r; blk < b1; blk += 4) {
        sum += partials[(long)blk * 128 + c];
        sq  += partials[(long)blk * 128 + 64 + c];
    }

    __shared__ float lsum[4][64];
    __shared__ float lsq[4][64];
    lsum[r][c] = sum;
    lsq[r][c]  = sq;
    __syncthreads();

    if (r == 0) {
        float tsum = ((lsum[0][c] + lsum[1][c]) + lsum[2][c]) + lsum[3][c];
        float tsq  = ((lsq[0][c]  + lsq[1][c])  + lsq[2][c])  + lsq[3][c];
        float cnt  = (float)(offs[s + 1] - offs[s]);
        float mean = tsum / cnt;
        float var  = tsq / cnt - mean * mean;
        float sc   = weight[c] * rsqrtf(var + EPS);
        scale[s * 64 + c] = sc;
        shift[s * 64 + c] = bias[c] - mean * sc;
    }
}

// ---------------------------------------------------------------- kernel 3
// y = x*scale + shift, float4 in / nt-float4 out, ascending streaming.
// Identical to R7/R9/R12 (proven): 4096 blocks x 256 threads x 16 float4.
#define K3_THREADS 256
#define K3_ITERS 16
__global__ __launch_bounds__(K3_THREADS) void pin_norm(
    const f32x4* __restrict__ x4, const int* __restrict__ bidx,
    const float4* __restrict__ scale4, const float4* __restrict__ shift4,
    f32x4* __restrict__ y4, long total4) {
    const long chunk = (long)blockIdx.x * (K3_THREADS * K3_ITERS);
    const int  tid   = threadIdx.x;
    const long p0    = chunk >> 4;
    const int  seg   = bidx[p0];
    const int  cgrp  = tid & 15;

    const float4 sc = scale4[seg * 16 + cgrp];
    const float4 sh = shift4[seg * 16 + cgrp];

    if (chunk + K3_THREADS * K3_ITERS <= total4) {
        #pragma unroll
        for (int k = 0; k < K3_ITERS; ++k) {
            long i = chunk + (long)k * K3_THREADS + tid;
            f32x4 v = x4[i];
            f32x4 o;
            o.x = v.x * sc.x + sh.x;
            o.y = v.y * sc.y + sh.y;
            o.z = v.z * sc.z + sh.z;
            o.w = v.w * sc.w + sh.w;
            __builtin_nontemporal_store(o, &y4[i]);
        }
    } else {
        for (int k = 0; k < K3_ITERS; ++k) {
            long i = chunk + (long)k * K3_THREADS + tid;
            if (i < total4) {
                f32x4 v = x4[i];
                f32x4 o;
                o.x = v.x * sc.x + sh.x;
                o.y = v.y * sc.y + sh.y;
                o.z = v.z * sc.z + sh.z;
                o.w = v.w * sc.w + sh.w;
                __builtin_nontemporal_store(o, &y4[i]);
            }
        }
    }
}

// ---------------------------------------------------------------- launcher
extern "C" void kernel_launch(void* const* d_in, const int* in_sizes, int n_in,
                              void* d_out, int out_size, void* d_ws, size_t ws_size,
                              hipStream_t stream) {
    const float* x       = (const float*)d_in[0];
    const float* weight  = (const float*)d_in[1];
    const float* bias    = (const float*)d_in[2];
    const int*   offs    = (const int*)d_in[3];
    const int*   bidx    = (const int*)d_in[4];
    float* out = (float*)d_out;

    const long C = in_sizes[1];          // 64
    const long N = (long)in_sizes[0] / C;
    const int  S = in_sizes[3] - 1;      // number of segments

    // ppb=512 -> 2048 chunks @ N=1M (8 blocks/CU, 32 waves/CU); partials 1 MB.
    int ppb = 512;
    long nb1;
    for (;;) {
        nb1 = (N + ppb - 1) / ppb;
        size_t need = (size_t)(nb1 * 128 + 2 * S * 64) * sizeof(float);
        if (need <= ws_size || ppb >= (1 << 20)) break;
        ppb <<= 1;
    }

    float* partials = (float*)d_ws;
    float* scale    = partials + nb1 * 128;
    float* shift    = scale + S * 64;

    pin_stats<<<(int)nb1, 256, 0, stream>>>((const float4*)x, partials, ppb, N);
    pin_scale<<<S, 256, 0, stream>>>(partials, weight, bias, offs, scale, shift, ppb);

    const long total4 = N * (C / 4);
    const long nb3 = (total4 + (K3_THREADS * K3_ITERS) - 1) / (K3_THREADS * K3_ITERS);
    pin_norm<<<(int)nb3, K3_THREADS, 0, stream>>>(
        (const f32x4*)x, bidx, (const float4*)scale, (const float4*)shift,
        (f32x4*)out, total4);
}

// Round 16
// 138.767 us; speedup vs baseline: 1.0523x; 1.0523x over previous
//
#include <hip/hip_runtime.h>
#include <hip/hip_bf16.h>

// PointInstanceNorm: per-(segment, channel) normalization over [1, N, C] fp32,
// S contiguous equal segments. FINAL config = R12 (137.0 us, best of 15 rounds).
//
// Structure:
//   K1: partial sum/sumsq, DESCENDING chunk sweep (leaves x resident in L3,
//       head most-recent), ppb=1024, DUAL-stream reads (two 1KB streams
//       128KB apart -- the only K1 win: 2.7 -> 3.5 TB/s cold read).
//   K2: parallel fold (8 blocks x 256 threads, 4 threads/channel + LDS tree).
//   K3: y = x*scale + shift, ascending; PLAIN x loads (L3-served: the full
//       256MB re-read is absorbed, proven by R6's FETCH=262MB fused run),
//       NON-TEMPORAL y stores (write stream must not evict x from L3).
//
// Measured structural ceiling (all levers exhausted):
//   K1 = 268MB cold read @ 3.5 TB/s = 77us. Cap invariant across unroll depth
//        (R9), 1/2/4 streams (R12/R13), sliding-window (R14), occupancy
//        16/32 waves per CU (R15). Consistent with m13: copy 6.29 TB/s =
//        ~3.15 read + ~3.15 write; write-only fills do 6.9 -- reads are the
//        slow direction on this part.
//   K3 = 268MB L3-read || 268MB nt-write = 55us (plain-store loses L3 reuse,
//        R5; nt-load and reverse traversal regress, R4).
//   K2 + 2 launch boundaries = 5us.
//   Total = 137us == measured. Roofline reached.

#define EPS 1e-5f

typedef float f32x4 __attribute__((ext_vector_type(4)));  // nt builtins reject HIP_vector_type

// ---------------------------------------------------------------- kernel 1
// 256 threads (4 waves), PPB=1024 contiguous points per chunk. Lane l reads
// the float4 of channels 4*(l&15)..+3 of point base+(l>>4): a wave covers
// 1KB contiguous per load. Fast path walks TWO streams (it, it+half ->
// 128KB apart), separate accumulators. Chunk index reversed (descending).
__global__ __launch_bounds__(256) void pin_stats(
    const float4* __restrict__ x4, float* __restrict__ partials,
    int ppb, long N) {
    const int tid   = threadIdx.x;
    const int lane  = tid & 63;
    const int wave  = tid >> 6;
    const int cgrp  = lane & 15;
    const int quart = lane >> 4;
    const long bchunk = (long)gridDim.x - 1 - blockIdx.x;   // descending sweep
    const long block_start = bchunk * ppb;

    float4 s = make_float4(0.f, 0.f, 0.f, 0.f);
    float4 q = make_float4(0.f, 0.f, 0.f, 0.f);

    const int iters = ppb >> 4;
    const long lane_base = (block_start + wave * 4 + quart) * 16 + cgrp;

    if (block_start + ppb <= N) {
        const int half = iters >> 1;                  // 32 at ppb=1024
        float4 s1 = make_float4(0.f, 0.f, 0.f, 0.f);
        float4 q1 = make_float4(0.f, 0.f, 0.f, 0.f);
        #pragma unroll 4
        for (int it = 0; it < half; ++it) {
            float4 a = x4[lane_base + (long)it * 256];
            float4 b = x4[lane_base + (long)(it + half) * 256];
            s.x  += a.x; s.y  += a.y; s.z  += a.z; s.w  += a.w;
            q.x  += a.x * a.x; q.y  += a.y * a.y; q.z  += a.z * a.z; q.w  += a.w * a.w;
            s1.x += b.x; s1.y += b.y; s1.z += b.z; s1.w += b.w;
            q1.x += b.x * b.x; q1.y += b.y * b.y; q1.z += b.z * b.z; q1.w += b.w * b.w;
        }
        s.x += s1.x; s.y += s1.y; s.z += s1.z; s.w += s1.w;
        q.x += q1.x; q.y += q1.y; q.z += q1.z; q.w += q1.w;
    } else {
        for (int it = 0; it < iters; ++it) {
            long p = block_start + (long)it * 16 + wave * 4 + quart;
            if (p < N) {
                float4 v = x4[p * 16 + cgrp];
                s.x += v.x; s.y += v.y; s.z += v.z; s.w += v.w;
                q.x += v.x * v.x; q.y += v.y * v.y; q.z += v.z * v.z; q.w += v.w * v.w;
            }
        }
    }

    #pragma unroll
    for (int off = 16; off <= 32; off <<= 1) {
        s.x += __shfl_xor(s.x, off); s.y += __shfl_xor(s.y, off);
        s.z += __shfl_xor(s.z, off); s.w += __shfl_xor(s.w, off);
        q.x += __shfl_xor(q.x, off); q.y += __shfl_xor(q.y, off);
        q.z += __shfl_xor(q.z, off); q.w += __shfl_xor(q.w, off);
    }

    __shared__ float lds[4][16][8];
    if (lane < 16) {
        lds[wave][lane][0] = s.x; lds[wave][lane][1] = s.y;
        lds[wave][lane][2] = s.z; lds[wave][lane][3] = s.w;
        lds[wave][lane][4] = q.x; lds[wave][lane][5] = q.y;
        lds[wave][lane][6] = q.z; lds[wave][lane][7] = q.w;
    }
    __syncthreads();

    if (tid < 128) {
        int stat = tid >> 6;
        int ch   = tid & 63;
        int cg   = ch >> 2;
        int j    = ch & 3;
        float v = lds[0][cg][stat * 4 + j] + lds[1][cg][stat * 4 + j]
                + lds[2][cg][stat * 4 + j] + lds[3][cg][stat * 4 + j];
        partials[bchunk * 128 + tid] = v;
    }
}

// ---------------------------------------------------------------- kernel 2
// One block per segment, 256 threads: 4 threads per channel fold interleaved
// chunk subsets, then a fixed-order LDS tree combines the 4 sub-partials.
__global__ __launch_bounds__(256) void pin_scale(
    const float* __restrict__ partials,
    const float* __restrict__ weight, const float* __restrict__ bias,
    const int* __restrict__ offs,
    float* __restrict__ scale, float* __restrict__ shift, int ppb) {
    const int s = blockIdx.x;
    const int c = threadIdx.x & 63;
    const int r = threadIdx.x >> 6;          // 0..3
    const int b0 = offs[s] / ppb;
    const int b1 = offs[s + 1] / ppb;

    float sum = 0.f, sq = 0.f;
    for (int blk = b0 + r; blk < b1; blk += 4) {
        sum += partials[(long)blk * 128 + c];
        sq  += partials[(long)blk * 128 + 64 + c];
    }

    __shared__ float lsum[4][64];
    __shared__ float lsq[4][64];
    lsum[r][c] = sum;
    lsq[r][c]  = sq;
    __syncthreads();

    if (r == 0) {
        float tsum = ((lsum[0][c] + lsum[1][c]) + lsum[2][c]) + lsum[3][c];
        float tsq  = ((lsq[0][c]  + lsq[1][c])  + lsq[2][c])  + lsq[3][c];
        float cnt  = (float)(offs[s + 1] - offs[s]);
        float mean = tsum / cnt;
        float var  = tsq / cnt - mean * mean;
        float sc   = weight[c] * rsqrtf(var + EPS);
        scale[s * 64 + c] = sc;
        shift[s * 64 + c] = bias[c] - mean * sc;
    }
}

// ---------------------------------------------------------------- kernel 3
// y = x*scale + shift, float4 in / nt-float4 out, ascending streaming.
// 4096 blocks x 256 threads x 16 float4 (proven since R7).
#define K3_THREADS 256
#define K3_ITERS 16
__global__ __launch_bounds__(K3_THREADS) void pin_norm(
    const f32x4* __restrict__ x4, const int* __restrict__ bidx,
    const float4* __restrict__ scale4, const float4* __restrict__ shift4,
    f32x4* __restrict__ y4, long total4) {
    const long chunk = (long)blockIdx.x * (K3_THREADS * K3_ITERS);
    const int  tid   = threadIdx.x;
    const long p0    = chunk >> 4;
    const int  seg   = bidx[p0];
    const int  cgrp  = tid & 15;

    const float4 sc = scale4[seg * 16 + cgrp];
    const float4 sh = shift4[seg * 16 + cgrp];

    if (chunk + K3_THREADS * K3_ITERS <= total4) {
        #pragma unroll
        for (int k = 0; k < K3_ITERS; ++k) {
            long i = chunk + (long)k * K3_THREADS + tid;
            f32x4 v = x4[i];
            f32x4 o;
            o.x = v.x * sc.x + sh.x;
            o.y = v.y * sc.y + sh.y;
            o.z = v.z * sc.z + sh.z;
            o.w = v.w * sc.w + sh.w;
            __builtin_nontemporal_store(o, &y4[i]);
        }
    } else {
        for (int k = 0; k < K3_ITERS; ++k) {
            long i = chunk + (long)k * K3_THREADS + tid;
            if (i < total4) {
                f32x4 v = x4[i];
                f32x4 o;
                o.x = v.x * sc.x + sh.x;
                o.y = v.y * sc.y + sh.y;
                o.z = v.z * sc.z + sh.z;
                o.w = v.w * sc.w + sh.w;
                __builtin_nontemporal_store(o, &y4[i]);
            }
        }
    }
}

// ---------------------------------------------------------------- launcher
extern "C" void kernel_launch(void* const* d_in, const int* in_sizes, int n_in,
                              void* d_out, int out_size, void* d_ws, size_t ws_size,
                              hipStream_t stream) {
    const float* x       = (const float*)d_in[0];
    const float* weight  = (const float*)d_in[1];
    const float* bias    = (const float*)d_in[2];
    const int*   offs    = (const int*)d_in[3];
    const int*   bidx    = (const int*)d_in[4];
    float* out = (float*)d_out;

    const long C = in_sizes[1];          // 64
    const long N = (long)in_sizes[0] / C;
    const int  S = in_sizes[3] - 1;      // number of segments

    // ppb=1024 (proven; 1024 chunks @ N=1M)
    int ppb = 1024;
    long nb1;
    for (;;) {
        nb1 = (N + ppb - 1) / ppb;
        size_t need = (size_t)(nb1 * 128 + 2 * S * 64) * sizeof(float);
        if (need <= ws_size || ppb >= (1 << 20)) break;
        ppb <<= 1;
    }

    float* partials = (float*)d_ws;
    float* scale    = partials + nb1 * 128;
    float* shift    = scale + S * 64;

    pin_stats<<<(int)nb1, 256, 0, stream>>>((const float4*)x, partials, ppb, N);
    pin_scale<<<S, 256, 0, stream>>>(partials, weight, bias, offs, scale, shift, ppb);

    const long total4 = N * (C / 4);
    const long nb3 = (total4 + (K3_THREADS * K3_ITERS) - 1) / (K3_THREADS * K3_ITERS);
    pin_norm<<<(int)nb3, K3_THREADS, 0, stream>>>(
        (const f32x4*)x, bidx, (const float4*)scale, (const float4*)shift,
        (f32x4*)out, total4);
}